// Round 4
// baseline (459.788 us; speedup 1.0000x reference)
//
#include <hip/hip_runtime.h>
#include <math.h>

#define B_  1024
#define T_  500
#define K_  100
#define NP_ 10000

__device__ __forceinline__ float lse2(float a, float b) {
    float m = fmaxf(a, b);
    return m + __logf(__expf(a - m) + __expf(b - m));
}

template<int CTRL, int RM>
__device__ __forceinline__ float dpp_add(float v) {
    int x = __builtin_amdgcn_update_dpp(0, __float_as_int(v), CTRL, RM, 0xf, true);
    return v + __int_as_float(x);
}

// Full-wave64 sum via DPP (pure VALU, no LDS). Result uniform via readlane(63).
__device__ __forceinline__ float wave_sum(float v) {
    v = dpp_add<0x111, 0xf>(v);   // row_shr:1
    v = dpp_add<0x112, 0xf>(v);   // row_shr:2
    v = dpp_add<0x114, 0xf>(v);   // row_shr:4
    v = dpp_add<0x118, 0xf>(v);   // row_shr:8
    v = dpp_add<0x142, 0xa>(v);   // row_bcast:15 -> rows 1,3
    v = dpp_add<0x143, 0xc>(v);   // row_bcast:31 -> rows 2,3
    return __int_as_float(__builtin_amdgcn_readlane(__float_as_int(v), 63));
}

// ---------------- precompute (indexed by the *kc* stream's values) ----------
// Qtab[p][s][o] = sum_k A[p,k] * log_softmax(trans,axis=1)[k][s][o]
// Stab[p]       = sum_k A[p,k]
// LOtab[p][s][o] = log_softmax(obs[p], over o)   (indexed by *problem* stream)
__global__ __launch_bounds__(64, 4) void bkt_pre(
    const float* __restrict__ A, const float* __restrict__ trans,
    const float* __restrict__ obs, float* __restrict__ Qtab,
    float* __restrict__ Stab, float* __restrict__ LOtab)
{
    const int p = blockIdx.x;
    const int lane = threadIdx.x;
    const int k0 = lane, k1 = lane + 64;
    const bool has1 = (k1 < K_);
    const int k1c = has1 ? k1 : k0;
    const float m1 = has1 ? 1.f : 0.f;

    float4 t0 = *reinterpret_cast<const float4*>(trans + k0 * 4);
    float l00 = lse2(t0.x, t0.z), l01 = lse2(t0.y, t0.w);
    float lt000 = t0.x - l00, lt001 = t0.y - l01;
    float lt010 = t0.z - l00, lt011 = t0.w - l01;
    float4 t1 = *reinterpret_cast<const float4*>(trans + k1c * 4);
    float l10 = lse2(t1.x, t1.z), l11 = lse2(t1.y, t1.w);
    float lt100 = t1.x - l10, lt101 = t1.y - l11;
    float lt110 = t1.z - l10, lt111 = t1.w - l11;

    const float* ar = A + (size_t)p * K_;
    float c0 = ar[k0];
    float c1 = ar[k1c] * m1;

    float sc  = wave_sum(c0 + c1);
    float q00 = wave_sum(c0 * lt000 + c1 * lt100);
    float q01 = wave_sum(c0 * lt001 + c1 * lt101);
    float q10 = wave_sum(c0 * lt010 + c1 * lt110);
    float q11 = wave_sum(c0 * lt011 + c1 * lt111);

    float4 ob = *reinterpret_cast<const float4*>(obs + (size_t)p * 4);
    float l0 = lse2(ob.x, ob.y), l1 = lse2(ob.z, ob.w);

    if (lane == 0) {
        reinterpret_cast<float4*>(Qtab)[p] = make_float4(q00, q01, q10, q11);
        Stab[p] = sc;
        reinterpret_cast<float4*>(LOtab)[p] =
            make_float4(ob.x - l0, ob.y - l0, ob.z - l1, ob.w - l1);
    }
}

// ---------------- main sequential scan ----------------
struct Raw { float c0, c1, S; float4 Q, L; int y; };
struct Der { float c0, c1, g00, g01, g10, g11, h00, h01, h10, h11; };

__global__ __launch_bounds__(64, 1) void bkt_main(
    const int* __restrict__ corr, const int* __restrict__ kc,
    const int* __restrict__ problem, const float* __restrict__ A,
    const float* __restrict__ init, const float* __restrict__ Qtab,
    const float* __restrict__ Stab, const float* __restrict__ LOtab,
    float* __restrict__ out)
{
    const int b = blockIdx.x;
    const int lane = threadIdx.x;
    const int k0 = lane, k1 = lane + 64;
    const bool has1 = (k1 < K_);
    const int k1c = has1 ? k1 : k0;
    const float m1 = has1 ? 1.f : 0.f;

    const int* kcb = kc + (size_t)b * T_;
    const int* prb = problem + (size_t)b * T_;
    const int* cob = corr + (size_t)b * T_;
    float* outp = out + (size_t)b * T_ * 2;

    // alpha init: log_softmax(init_logits, axis=1); invalid k1 lanes -> 0 (never used: c1=0)
    float al00, al01, al10 = 0.f, al11 = 0.f;
    {
        float2 x = *reinterpret_cast<const float2*>(init + k0 * 2);
        float l = lse2(x.x, x.y);
        al00 = x.x - l; al01 = x.y - l;
    }
    {
        float2 x = *reinterpret_cast<const float2*>(init + k1c * 2);
        float l = lse2(x.x, x.y);
        al10 = (x.x - l) * m1; al11 = (x.y - l) * m1;
    }

    // Q and S are functions of the kc stream; L of the problem stream.
#define ISSUE(raw, kcv, prv, yv) {                                        \
        const float* ar_ = A + (size_t)(kcv) * K_;                        \
        raw.c0 = ar_[k0];                                                 \
        raw.c1 = ar_[k1c] * m1;                                           \
        raw.Q = reinterpret_cast<const float4*>(Qtab)[(size_t)(kcv)];     \
        raw.S = Stab[(size_t)(kcv)];                                      \
        raw.L = reinterpret_cast<const float4*>(LOtab)[(size_t)(prv)];    \
        raw.y = (yv); }

#define DERIVE(d, raw) {                                                  \
        d.h00 = raw.L.x * raw.S; d.h01 = raw.L.y * raw.S;                 \
        d.h10 = raw.L.z * raw.S; d.h11 = raw.L.w * raw.S;                 \
        float ol0 = (raw.y == 0) ? d.h00 : d.h01;                         \
        float ol1 = (raw.y == 0) ? d.h10 : d.h11;                         \
        d.g00 = ol0 + raw.Q.x; d.g01 = ol1 + raw.Q.y;                     \
        d.g10 = ol0 + raw.Q.z; d.g11 = ol1 + raw.Q.w;                     \
        d.c0 = raw.c0; d.c1 = raw.c1; }

#define STEP(t, d) {                                                      \
        float p0 = d.c0 * al00 + d.c1 * al10;                             \
        float p1 = d.c0 * al01 + d.c1 * al11;                             \
        float a20 = wave_sum(p0);                                         \
        float a21 = wave_sum(p1);                                         \
        float a30 = lse2(d.g00 + a20, d.g01 + a21);                       \
        float a31 = lse2(d.g10 + a20, d.g11 + a21);                       \
        al00 += d.c0 * (a30 - al00);                                      \
        al01 += d.c0 * (a31 - al01);                                      \
        al10 += d.c1 * (a30 - al10);                                      \
        al11 += d.c1 * (a31 - al11);                                      \
        float py0 = lse2(d.h00 + a20, d.h10 + a21);                       \
        float py1 = lse2(d.h01 + a20, d.h11 + a21);                       \
        float nrm = lse2(py0, py1);                                       \
        if (lane == 0 && (t) < T_) {                                      \
            *reinterpret_cast<float2*>(outp + (size_t)(t) * 2) =          \
                make_float2(py0 - nrm, py1 - nrm);                        \
        } }

    // clamped index load into one of the two index generations (i or j)
#define LOADIDX_I(tt0) {                                                  \
        int t0_ = (tt0) < T_ ? (tt0) : T_ - 1;                            \
        int t1_ = (tt0) + 1 < T_ ? (tt0) + 1 : T_ - 1;                    \
        int t2_ = (tt0) + 2 < T_ ? (tt0) + 2 : T_ - 1;                    \
        int t3_ = (tt0) + 3 < T_ ? (tt0) + 3 : T_ - 1;                    \
        ki0 = kcb[t0_]; pi0 = prb[t0_]; yi0 = cob[t0_];                   \
        ki1 = kcb[t1_]; pi1 = prb[t1_]; yi1 = cob[t1_];                   \
        ki2 = kcb[t2_]; pi2 = prb[t2_]; yi2 = cob[t2_];                   \
        ki3 = kcb[t3_]; pi3 = prb[t3_]; yi3 = cob[t3_]; }

#define LOADIDX_J(tt0) {                                                  \
        int t0_ = (tt0) < T_ ? (tt0) : T_ - 1;                            \
        int t1_ = (tt0) + 1 < T_ ? (tt0) + 1 : T_ - 1;                    \
        int t2_ = (tt0) + 2 < T_ ? (tt0) + 2 : T_ - 1;                    \
        int t3_ = (tt0) + 3 < T_ ? (tt0) + 3 : T_ - 1;                    \
        kj0 = kcb[t0_]; pj0 = prb[t0_]; yj0 = cob[t0_];                   \
        kj1 = kcb[t1_]; pj1 = prb[t1_]; yj1 = cob[t1_];                   \
        kj2 = kcb[t2_]; pj2 = prb[t2_]; yj2 = cob[t2_]; \
        kj3 = kcb[t3_]; pj3 = prb[t3_]; yj3 = cob[t3_]; }

    Raw rA, rB, rC, rD, sA, sB, sC, sD;
    Der dA, dB, dC, dD;
    int ki0, ki1, ki2, ki3, pi0, pi1, pi2, pi3, yi0, yi1, yi2, yi3;
    int kj0, kj1, kj2, kj3, pj0, pj1, pj2, pj3, yj0, yj1, yj2, yj3;

    // ---- prologue ----
    LOADIDX_I(0);                       // steps 0..3
    ISSUE(sA, ki0, pi0, yi0); ISSUE(sB, ki1, pi1, yi1);
    ISSUE(sC, ki2, pi2, yi2); ISSUE(sD, ki3, pi3, yi3);
    LOADIDX_I(4);                       // steps 4..7
    ISSUE(rA, ki0, pi0, yi0); ISSUE(rB, ki1, pi1, yi1);
    ISSUE(rC, ki2, pi2, yi2); ISSUE(rD, ki3, pi3, yi3);
    LOADIDX_I(8);                       // steps 8..11  (gen i)
    LOADIDX_J(12);                      // steps 12..15 (gen j)
    DERIVE(dA, sA); DERIVE(dB, sB); DERIVE(dC, sC); DERIVE(dD, sD);

    // ---- main loop: 8 steps per body ----
    // entry invariant: dA..dD = steps t..t+3; rA..rD in flight for t+4..t+7;
    //                  gen-i idx = t+8..t+11; gen-j idx = t+12..t+15
#pragma unroll 1
    for (int t = 0; t < T_; t += 8) {
        ISSUE(sA, ki0, pi0, yi0); ISSUE(sB, ki1, pi1, yi1);     // steps t+8..t+11
        ISSUE(sC, ki2, pi2, yi2); ISSUE(sD, ki3, pi3, yi3);
        LOADIDX_I(t + 16);                                      // steps t+16..t+19
        STEP(t + 0, dA); STEP(t + 1, dB); STEP(t + 2, dC); STEP(t + 3, dD);
        DERIVE(dA, rA); DERIVE(dB, rB); DERIVE(dC, rC); DERIVE(dD, rD);

        ISSUE(rA, kj0, pj0, yj0); ISSUE(rB, kj1, pj1, yj1);     // steps t+12..t+15
        ISSUE(rC, kj2, pj2, yj2); ISSUE(rD, kj3, pj3, yj3);
        LOADIDX_J(t + 20);                                      // steps t+20..t+23
        STEP(t + 4, dA); STEP(t + 5, dB); STEP(t + 6, dC); STEP(t + 7, dD);
        DERIVE(dA, sA); DERIVE(dB, sB); DERIVE(dC, sC); DERIVE(dD, sD);
    }
#undef ISSUE
#undef DERIVE
#undef STEP
#undef LOADIDX_I
#undef LOADIDX_J
}

extern "C" void kernel_launch(void* const* d_in, const int* in_sizes, int n_in,
                              void* d_out, int out_size, void* d_ws, size_t ws_size,
                              hipStream_t stream) {
    const int*   corr    = (const int*)d_in[0];
    const int*   kc      = (const int*)d_in[1];
    const int*   problem = (const int*)d_in[2];
    const float* A       = (const float*)d_in[3];
    const float* trans   = (const float*)d_in[4];
    const float* obs     = (const float*)d_in[5];
    const float* init    = (const float*)d_in[6];
    float* out = (float*)d_out;

    // workspace layout: Qtab (NP*4 f32) | LOtab (NP*4 f32) | Stab (NP f32)
    float* Qtab  = (float*)d_ws;
    float* LOtab = Qtab + (size_t)NP_ * 4;
    float* Stab  = LOtab + (size_t)NP_ * 4;

    bkt_pre<<<NP_, 64, 0, stream>>>(A, trans, obs, Qtab, Stab, LOtab);
    bkt_main<<<B_, 64, 0, stream>>>(corr, kc, problem, A, init, Qtab, Stab, LOtab, out);
}

// Round 5
// 335.482 us; speedup vs baseline: 1.3705x; 1.3705x over previous
//
#include <hip/hip_runtime.h>
#include <math.h>

#define B_  1024
#define T_  500
#define K_  100
#define NP_ 10000
#define CH  32          // steps per chunk
#define NCH 16          // 16*32 = 512 >= T_

__device__ __forceinline__ float lse2(float a, float b) {
    float m = fmaxf(a, b);
    return m + __logf(__expf(a - m) + __expf(b - m));
}

template<int CTRL, int RM>
__device__ __forceinline__ float dpp_add(float v) {
    int x = __builtin_amdgcn_update_dpp(0, __float_as_int(v), CTRL, RM, 0xf, true);
    return v + __int_as_float(x);
}

// Full-wave64 sum via DPP (pure VALU, no LDS). Result uniform via readlane(63).
__device__ __forceinline__ float wave_sum(float v) {
    v = dpp_add<0x111, 0xf>(v);   // row_shr:1
    v = dpp_add<0x112, 0xf>(v);   // row_shr:2
    v = dpp_add<0x114, 0xf>(v);   // row_shr:4
    v = dpp_add<0x118, 0xf>(v);   // row_shr:8
    v = dpp_add<0x142, 0xa>(v);   // row_bcast:15 -> rows 1,3
    v = dpp_add<0x143, 0xc>(v);   // row_bcast:31 -> rows 2,3
    return __int_as_float(__builtin_amdgcn_readlane(__float_as_int(v), 63));
}

// async global->LDS DMA: per-lane global src, linear LDS dest (base + lane*size)
#define GLOAD16(gp, lp) __builtin_amdgcn_global_load_lds( \
    (const __attribute__((address_space(1))) unsigned int*)(gp), \
    (__attribute__((address_space(3))) unsigned int*)(lp), 16, 0, 0)
#define GLOAD4(gp, lp) __builtin_amdgcn_global_load_lds( \
    (const __attribute__((address_space(1))) unsigned int*)(gp), \
    (__attribute__((address_space(3))) unsigned int*)(lp), 4, 0, 0)
#define WAITV0 asm volatile("s_waitcnt vmcnt(0)" ::: "memory")

// ---------------- precompute (unchanged from round 3) ----------
__global__ __launch_bounds__(64, 4) void bkt_pre(
    const float* __restrict__ A, const float* __restrict__ trans,
    const float* __restrict__ obs, float* __restrict__ Qtab,
    float* __restrict__ Stab, float* __restrict__ LOtab)
{
    const int p = blockIdx.x;
    const int lane = threadIdx.x;
    const int k0 = lane, k1 = lane + 64;
    const bool has1 = (k1 < K_);
    const int k1c = has1 ? k1 : k0;
    const float m1 = has1 ? 1.f : 0.f;

    float4 t0 = *reinterpret_cast<const float4*>(trans + k0 * 4);
    float l00 = lse2(t0.x, t0.z), l01 = lse2(t0.y, t0.w);
    float lt000 = t0.x - l00, lt001 = t0.y - l01;
    float lt010 = t0.z - l00, lt011 = t0.w - l01;
    float4 t1 = *reinterpret_cast<const float4*>(trans + k1c * 4);
    float l10 = lse2(t1.x, t1.z), l11 = lse2(t1.y, t1.w);
    float lt100 = t1.x - l10, lt101 = t1.y - l11;
    float lt110 = t1.z - l10, lt111 = t1.w - l11;

    const float* ar = A + (size_t)p * K_;
    float c0 = ar[k0];
    float c1 = ar[k1c] * m1;

    float sc  = wave_sum(c0 + c1);
    float q00 = wave_sum(c0 * lt000 + c1 * lt100);
    float q01 = wave_sum(c0 * lt001 + c1 * lt101);
    float q10 = wave_sum(c0 * lt010 + c1 * lt110);
    float q11 = wave_sum(c0 * lt011 + c1 * lt111);

    float4 ob = *reinterpret_cast<const float4*>(obs + (size_t)p * 4);
    float l0 = lse2(ob.x, ob.y), l1 = lse2(ob.z, ob.w);

    if (lane == 0) {
        reinterpret_cast<float4*>(Qtab)[p] = make_float4(q00, q01, q10, q11);
        Stab[p] = sc;
        reinterpret_cast<float4*>(LOtab)[p] =
            make_float4(ob.x - l0, ob.y - l0, ob.z - l1, ob.w - l1);
    }
}

// ---------------- main sequential scan: chunked LDS staging ----------------
struct Raw { float c0, c1, S; float4 Q, L; int y; };
struct Der { float c0, c1, g00, g01, g10, g11, h00, h01, h10, h11; };

__global__ __launch_bounds__(64, 1) void bkt_main(
    const int* __restrict__ corr, const int* __restrict__ kc,
    const int* __restrict__ problem, const float* __restrict__ A,
    const float* __restrict__ init, const float* __restrict__ Qtab,
    const float* __restrict__ Stab, const float* __restrict__ LOtab,
    float* __restrict__ out)
{
    const int b = blockIdx.x;
    const int lane = threadIdx.x;
    const int k1 = lane + 64;
    const bool has1 = (k1 < K_);
    const int k1c = has1 ? k1 : lane;
    const float m1 = has1 ? 1.f : 0.f;

    // LDS staging buffers (29 KB total -> 4+ blocks/CU)
    __shared__ float s_c[2][CH * K_];        // A-rows per step      25600 B
    __shared__ float4 s_ql[2][2 * CH];       // Q[0..31] L[32..63]    2048 B
    __shared__ float s_s[2][CH];             //                        256 B
    __shared__ int  s_kcpr[3][2 * CH];       // kc[0..31] pr[32..63]   768 B
    __shared__ int  s_y[3][CH];              //                        384 B

    const int* kcb = kc + (size_t)b * T_;
    const int* prb = problem + (size_t)b * T_;
    const int* cob = corr + (size_t)b * T_;
    float* outp = out + (size_t)b * T_ * 2;

    // alpha init: log_softmax(init_logits, axis=1)
    float al00, al01, al10 = 0.f, al11 = 0.f;
    {
        float2 x = *reinterpret_cast<const float2*>(init + lane * 2);
        float l = lse2(x.x, x.y);
        al00 = x.x - l; al01 = x.y - l;
    }
    {
        float2 x = *reinterpret_cast<const float2*>(init + k1c * 2);
        float l = lse2(x.x, x.y);
        al10 = (x.x - l) * m1; al11 = (x.y - l) * m1;
    }

    // stage kc/pr (combined) + y indices for chunk `cn` into idx buffer ib
#define STAGEIDX(cn, ib) {                                                \
        int tt_ = (cn) * CH + (lane & 31);                                \
        tt_ = tt_ < T_ ? tt_ : T_ - 1;                                    \
        const int* is_ = (lane < 32 ? kcb : prb) + tt_;                   \
        GLOAD4(is_, &s_kcpr[ib][0]);                                      \
        if (lane < 32) GLOAD4(cob + tt_, &s_y[ib][0]);                    \
    }

    // issue DMA gathers for chunk `cn` (idx buffer ib, data buffer db)
#define GATHER(ib, db) {                                                  \
        int myidx_ = s_kcpr[ib][lane];                                    \
        const float* qlsrc_ = (lane < 32)                                 \
            ? (Qtab  + (size_t)myidx_ * 4)                                \
            : (LOtab + (size_t)myidx_ * 4);                               \
        GLOAD16(qlsrc_, &s_ql[db][0]);                                    \
        if (lane < 32) GLOAD4(Stab + myidx_, &s_s[db][0]);                \
        _Pragma("unroll")                                                 \
        for (int j_ = 0; j_ < 13; ++j_) {                                 \
            int f_ = j_ * 64 + lane;                                      \
            unsigned tf_ = ((unsigned)f_ * 5243u) >> 17;    /* f/25 */    \
            int q_ = f_ - (int)tf_ * 25;                                  \
            int kcv_ = s_kcpr[ib][tf_];                                   \
            const float* asrc_ = A + (size_t)kcv_ * K_ + q_ * 4;          \
            if (f_ < CH * 25) GLOAD16(asrc_, &s_c[db][j_ * 256]);         \
        }                                                                 \
    }

#define LDSTEP(rr, cb_, qlb_, sb_, yb_, tt) {                             \
        rr.c0 = cb_[(tt) * K_ + lane];                                    \
        rr.c1 = cb_[(tt) * K_ + k1c] * m1;                                \
        rr.Q = qlb_[(tt)];                                                \
        rr.L = qlb_[CH + (tt)];                                           \
        rr.S = sb_[(tt)];                                                 \
        rr.y = yb_[(tt)]; }

#define DERIVE(d, raw) {                                                  \
        d.h00 = raw.L.x * raw.S; d.h01 = raw.L.y * raw.S;                 \
        d.h10 = raw.L.z * raw.S; d.h11 = raw.L.w * raw.S;                 \
        float ol0 = (raw.y == 0) ? d.h00 : d.h01;                         \
        float ol1 = (raw.y == 0) ? d.h10 : d.h11;                         \
        d.g00 = ol0 + raw.Q.x; d.g01 = ol1 + raw.Q.y;                     \
        d.g10 = ol0 + raw.Q.z; d.g11 = ol1 + raw.Q.w;                     \
        d.c0 = raw.c0; d.c1 = raw.c1; }

#define STEP(t, d) {                                                      \
        float p0 = d.c0 * al00 + d.c1 * al10;                             \
        float p1 = d.c0 * al01 + d.c1 * al11;                             \
        float a20 = wave_sum(p0);                                         \
        float a21 = wave_sum(p1);                                         \
        float a30 = lse2(d.g00 + a20, d.g01 + a21);                       \
        float a31 = lse2(d.g10 + a20, d.g11 + a21);                       \
        al00 += d.c0 * (a30 - al00);                                      \
        al01 += d.c0 * (a31 - al01);                                      \
        al10 += d.c1 * (a30 - al10);                                      \
        al11 += d.c1 * (a31 - al11);                                      \
        float py0 = lse2(d.h00 + a20, d.h10 + a21);                       \
        float py1 = lse2(d.h01 + a20, d.h11 + a21);                       \
        float nrm = lse2(py0, py1);                                       \
        if (lane == 0 && (t) < T_) {                                      \
            *reinterpret_cast<float2*>(outp + (size_t)(t) * 2) =          \
                make_float2(py0 - nrm, py1 - nrm);                        \
        } }

    // ---- prologue: stage idx for chunks 0,1; gather chunk 0 ----
    STAGEIDX(0, 0);
    STAGEIDX(1, 1);
    WAITV0;
    GATHER(0, 0);

    Raw rE, rF; Der dE, dF;

#pragma unroll 1
    for (int n = 0; n < NCH; ++n) {
        WAITV0;                               // chunk-n data + idx n+1 landed
        {
            int i2 = (n + 2) % 3;
            STAGEIDX(n + 2, i2);
        }
        {
            int i1 = (n + 1) % 3, d1 = (n + 1) & 1;
            GATHER(i1, d1);
        }
        // ---- compute chunk n from LDS (2-deep register pipeline) ----
        {
            const float*  cb  = s_c[n & 1];
            const float4* qlb = s_ql[n & 1];
            const float*  sb  = s_s[n & 1];
            const int*    yb  = s_y[n % 3];
            const int base = n * CH;

            LDSTEP(rE, cb, qlb, sb, yb, 0);
            LDSTEP(rF, cb, qlb, sb, yb, 1);
            DERIVE(dE, rE);
#pragma unroll 4
            for (int u = 0; u < CH; u += 2) {
                if (u + 2 < CH) LDSTEP(rE, cb, qlb, sb, yb, u + 2);
                DERIVE(dF, rF);
                STEP(base + u, dE);
                if (u + 3 < CH) LDSTEP(rF, cb, qlb, sb, yb, u + 3);
                DERIVE(dE, rE);
                STEP(base + u + 1, dF);
            }
        }
    }
#undef STAGEIDX
#undef GATHER
#undef LDSTEP
#undef DERIVE
#undef STEP
}

extern "C" void kernel_launch(void* const* d_in, const int* in_sizes, int n_in,
                              void* d_out, int out_size, void* d_ws, size_t ws_size,
                              hipStream_t stream) {
    const int*   corr    = (const int*)d_in[0];
    const int*   kc      = (const int*)d_in[1];
    const int*   problem = (const int*)d_in[2];
    const float* A       = (const float*)d_in[3];
    const float* trans   = (const float*)d_in[4];
    const float* obs     = (const float*)d_in[5];
    const float* init    = (const float*)d_in[6];
    float* out = (float*)d_out;

    // workspace layout: Qtab (NP*4 f32) | LOtab (NP*4 f32) | Stab (NP f32)
    float* Qtab  = (float*)d_ws;
    float* LOtab = Qtab + (size_t)NP_ * 4;
    float* Stab  = LOtab + (size_t)NP_ * 4;

    bkt_pre<<<NP_, 64, 0, stream>>>(A, trans, obs, Qtab, Stab, LOtab);
    bkt_main<<<B_, 64, 0, stream>>>(corr, kc, problem, A, init, Qtab, Stab, LOtab, out);
}

// Round 6
// 251.045 us; speedup vs baseline: 1.8315x; 1.3363x over previous
//
#include <hip/hip_runtime.h>
#include <math.h>

#define B_  1024
#define T_  500
#define K_  100
#define NP_ 10000
#define CH  32          // steps per chunk
#define NCH 16          // 16*32 = 512 >= T_

__device__ __forceinline__ float lse2(float a, float b) {
    float m = fmaxf(a, b);
    return m + __logf(__expf(a - m) + __expf(b - m));
}

template<int CTRL, int RM>
__device__ __forceinline__ float dpp_add(float v) {
    int x = __builtin_amdgcn_update_dpp(0, __float_as_int(v), CTRL, RM, 0xf, true);
    return v + __int_as_float(x);
}

// Full-wave64 sum via DPP (pure VALU, no LDS). Result uniform via readlane(63).
__device__ __forceinline__ float wave_sum(float v) {
    v = dpp_add<0x111, 0xf>(v);   // row_shr:1
    v = dpp_add<0x112, 0xf>(v);   // row_shr:2
    v = dpp_add<0x114, 0xf>(v);   // row_shr:4
    v = dpp_add<0x118, 0xf>(v);   // row_shr:8
    v = dpp_add<0x142, 0xa>(v);   // row_bcast:15 -> rows 1,3
    v = dpp_add<0x143, 0xc>(v);   // row_bcast:31 -> rows 2,3
    return __int_as_float(__builtin_amdgcn_readlane(__float_as_int(v), 63));
}

// async global->LDS DMA: per-lane global src, linear LDS dest (base + lane*size)
#define GLOAD16(gp, lp) __builtin_amdgcn_global_load_lds( \
    (const __attribute__((address_space(1))) unsigned int*)(gp), \
    (__attribute__((address_space(3))) unsigned int*)(lp), 16, 0, 0)
#define GLOAD4(gp, lp) __builtin_amdgcn_global_load_lds( \
    (const __attribute__((address_space(1))) unsigned int*)(gp), \
    (__attribute__((address_space(3))) unsigned int*)(lp), 4, 0, 0)
#define WAITV0 asm volatile("s_waitcnt vmcnt(0)" ::: "memory")

// ---------------- precompute (unchanged, validated) ----------
__global__ __launch_bounds__(64, 4) void bkt_pre(
    const float* __restrict__ A, const float* __restrict__ trans,
    const float* __restrict__ obs, float* __restrict__ Qtab,
    float* __restrict__ Stab, float* __restrict__ LOtab)
{
    const int p = blockIdx.x;
    const int lane = threadIdx.x;
    const int k0 = lane, k1 = lane + 64;
    const bool has1 = (k1 < K_);
    const int k1c = has1 ? k1 : k0;
    const float m1 = has1 ? 1.f : 0.f;

    float4 t0 = *reinterpret_cast<const float4*>(trans + k0 * 4);
    float l00 = lse2(t0.x, t0.z), l01 = lse2(t0.y, t0.w);
    float lt000 = t0.x - l00, lt001 = t0.y - l01;
    float lt010 = t0.z - l00, lt011 = t0.w - l01;
    float4 t1 = *reinterpret_cast<const float4*>(trans + k1c * 4);
    float l10 = lse2(t1.x, t1.z), l11 = lse2(t1.y, t1.w);
    float lt100 = t1.x - l10, lt101 = t1.y - l11;
    float lt110 = t1.z - l10, lt111 = t1.w - l11;

    const float* ar = A + (size_t)p * K_;
    float c0 = ar[k0];
    float c1 = ar[k1c] * m1;

    float sc  = wave_sum(c0 + c1);
    float q00 = wave_sum(c0 * lt000 + c1 * lt100);
    float q01 = wave_sum(c0 * lt001 + c1 * lt101);
    float q10 = wave_sum(c0 * lt010 + c1 * lt110);
    float q11 = wave_sum(c0 * lt011 + c1 * lt111);

    float4 ob = *reinterpret_cast<const float4*>(obs + (size_t)p * 4);
    float l0 = lse2(ob.x, ob.y), l1 = lse2(ob.z, ob.w);

    if (lane == 0) {
        reinterpret_cast<float4*>(Qtab)[p] = make_float4(q00, q01, q10, q11);
        Stab[p] = sc;
        reinterpret_cast<float4*>(LOtab)[p] =
            make_float4(ob.x - l0, ob.y - l0, ob.z - l1, ob.w - l1);
    }
}

// ---------------- main sequential scan: U/W short-chain + epilogue py ------
__global__ __launch_bounds__(64, 1) void bkt_main(
    const int* __restrict__ corr, const int* __restrict__ kc,
    const int* __restrict__ problem, const float* __restrict__ A,
    const float* __restrict__ init, const float* __restrict__ Qtab,
    const float* __restrict__ Stab, const float* __restrict__ LOtab,
    float* __restrict__ out)
{
    const int b = blockIdx.x;
    const int lane = threadIdx.x;
    const int k1 = lane + 64;
    const bool has1 = (k1 < K_);
    const int k1c = has1 ? k1 : lane;
    const float m1 = has1 ? 1.f : 0.f;

    // LDS staging buffers (~29.4 KB)
    __shared__ float  s_c[2][CH * K_];       // A-rows per step      25600 B
    __shared__ float4 s_ql[2][2 * CH];       // Q[0..31] L[32..63]    2048 B
    __shared__ float  s_s[2][CH];            //                        256 B
    __shared__ int    s_kcpr[3][2 * CH];     // kc[0..31] pr[32..63]   768 B
    __shared__ int    s_y[3][CH];            //                        384 B
    __shared__ float2 s_a2[CH];              // per-step a2 scalars    256 B

    const int* kcb = kc + (size_t)b * T_;
    const int* prb = problem + (size_t)b * T_;
    const int* cob = corr + (size_t)b * T_;
    float* outp = out + (size_t)b * T_ * 2;

    // alpha init: log_softmax(init_logits, axis=1)
    float al00, al01, al10 = 0.f, al11 = 0.f;
    {
        float2 x = *reinterpret_cast<const float2*>(init + lane * 2);
        float l = lse2(x.x, x.y);
        al00 = x.x - l; al01 = x.y - l;
    }
    {
        float2 x = *reinterpret_cast<const float2*>(init + k1c * 2);
        float l = lse2(x.x, x.y);
        al10 = (x.x - l) * m1; al11 = (x.y - l) * m1;
    }

#define STAGEIDX(cn, ib) {                                                \
        int tt_ = (cn) * CH + (lane & 31);                                \
        tt_ = tt_ < T_ ? tt_ : T_ - 1;                                    \
        const int* is_ = (lane < 32 ? kcb : prb) + tt_;                   \
        GLOAD4(is_, &s_kcpr[ib][0]);                                      \
        if (lane < 32) GLOAD4(cob + tt_, &s_y[ib][0]);                    \
    }

#define GATHER(ib, db) {                                                  \
        int myidx_ = s_kcpr[ib][lane];                                    \
        const float* qlsrc_ = (lane < 32)                                 \
            ? (Qtab  + (size_t)myidx_ * 4)                                \
            : (LOtab + (size_t)myidx_ * 4);                               \
        GLOAD16(qlsrc_, &s_ql[db][0]);                                    \
        if (lane < 32) GLOAD4(Stab + myidx_, &s_s[db][0]);                \
        _Pragma("unroll")                                                 \
        for (int j_ = 0; j_ < 13; ++j_) {                                 \
            int f_ = j_ * 64 + lane;                                      \
            unsigned tf_ = ((unsigned)f_ * 5243u) >> 17;    /* f/25 */    \
            int q_ = f_ - (int)tf_ * 25;                                  \
            int kcv_ = s_kcpr[ib][tf_];                                   \
            const float* asrc_ = A + (size_t)kcv_ * K_ + q_ * 4;          \
            if (f_ < CH * 25) GLOAD16(asrc_, &s_c[db][j_ * 256]);         \
        }                                                                 \
    }

    // ---- prologue: stage idx for chunks 0,1; gather chunk 0 ----
    STAGEIDX(0, 0);
    STAGEIDX(1, 1);
    WAITV0;
    GATHER(0, 0);

#pragma unroll 1
    for (int n = 0; n < NCH; ++n) {
        WAITV0;                               // chunk-n data + idx n+1 landed
        { int i2 = (n + 2) % 3; STAGEIDX(n + 2, i2); }
        { int i1 = (n + 1) % 3, d1 = (n + 1) & 1; GATHER(i1, d1); }

        const float*  cbuf = s_c[n & 1];
        const float4* qlb  = s_ql[n & 1];
        const float*  sb   = s_s[n & 1];
        const int*    yb   = s_y[n % 3];
        const int base = n * CH;

        // ---- prime a2 for step base+0 from fresh alpha ----
        float ca0 = cbuf[lane];
        float ca1 = cbuf[k1c] * m1;
        float a20 = wave_sum(ca0 * al00 + ca1 * al10);
        float a21 = wave_sum(ca0 * al01 + ca1 * al11);

        // ---- steps 0..CH-2: short-chain recurrence ----
#pragma unroll 2
        for (int u = 0; u < CH - 1; ++u) {
            float cb0 = cbuf[(u + 1) * K_ + lane];
            float cb1 = cbuf[(u + 1) * K_ + k1c] * m1;
            float4 Q = qlb[u];
            float4 L = qlb[CH + u];
            float  S = sb[u];
            int    y = yb[u];
            if (lane == 0) s_a2[u] = make_float2(a20, a21);
            float hs0 = ((y == 0) ? L.x : L.y) * S;
            float hs1 = ((y == 0) ? L.z : L.w) * S;
            // critical scalar chain
            float a30 = lse2(hs0 + Q.x + a20, hs1 + Q.y + a21);
            float a31 = lse2(hs0 + Q.z + a20, hs1 + Q.w + a21);
            // U/W wave-sums: independent of a3, issue under the lse2 latency
            float tu0 = cb0 * (1.f - ca0), tu1 = cb1 * (1.f - ca1);
            float U0 = wave_sum(tu0 * al00 + tu1 * al10);
            float U1 = wave_sum(tu0 * al01 + tu1 * al11);
            float Wv = wave_sum(cb0 * ca0 + cb1 * ca1);
            // alpha update (uses pre-update alpha in U above: source order)
            al00 += ca0 * (a30 - al00);
            al01 += ca0 * (a31 - al01);
            al10 += ca1 * (a30 - al10);
            al11 += ca1 * (a31 - al11);
            // next a2 = U + W*a3
            a20 = U0 + Wv * a30;
            a21 = U1 + Wv * a31;
            ca0 = cb0; ca1 = cb1;
        }
        // ---- last step of chunk (no next-a2 needed) ----
        {
            const int u = CH - 1;
            float4 Q = qlb[u];
            float4 L = qlb[CH + u];
            float  S = sb[u];
            int    y = yb[u];
            if (lane == 0) s_a2[u] = make_float2(a20, a21);
            float hs0 = ((y == 0) ? L.x : L.y) * S;
            float hs1 = ((y == 0) ? L.z : L.w) * S;
            float a30 = lse2(hs0 + Q.x + a20, hs1 + Q.y + a21);
            float a31 = lse2(hs0 + Q.z + a20, hs1 + Q.w + a21);
            al00 += ca0 * (a30 - al00);
            al01 += ca0 * (a31 - al01);
            al10 += ca1 * (a30 - al10);
            al11 += ca1 * (a31 - al11);
        }
        // ---- epilogue: batched py for the chunk (lanes 0..31, one step each) ----
        if (lane < 32) {
            float2 a2v = s_a2[lane];
            float4 L = qlb[CH + lane];
            float  S = sb[lane];
            float h00 = L.x * S, h01 = L.y * S, h10 = L.z * S, h11 = L.w * S;
            float py0 = lse2(h00 + a2v.x, h10 + a2v.y);
            float py1 = lse2(h01 + a2v.x, h11 + a2v.y);
            float nrm = lse2(py0, py1);
            int t = base + lane;
            if (t < T_)
                *reinterpret_cast<float2*>(outp + (size_t)t * 2) =
                    make_float2(py0 - nrm, py1 - nrm);
        }
    }
#undef STAGEIDX
#undef GATHER
}

extern "C" void kernel_launch(void* const* d_in, const int* in_sizes, int n_in,
                              void* d_out, int out_size, void* d_ws, size_t ws_size,
                              hipStream_t stream) {
    const int*   corr    = (const int*)d_in[0];
    const int*   kc      = (const int*)d_in[1];
    const int*   problem = (const int*)d_in[2];
    const float* A       = (const float*)d_in[3];
    const float* trans   = (const float*)d_in[4];
    const float* obs     = (const float*)d_in[5];
    const float* init    = (const float*)d_in[6];
    float* out = (float*)d_out;

    // workspace layout: Qtab (NP*4 f32) | LOtab (NP*4 f32) | Stab (NP f32)
    float* Qtab  = (float*)d_ws;
    float* LOtab = Qtab + (size_t)NP_ * 4;
    float* Stab  = LOtab + (size_t)NP_ * 4;

    bkt_pre<<<NP_, 64, 0, stream>>>(A, trans, obs, Qtab, Stab, LOtab);
    bkt_main<<<B_, 64, 0, stream>>>(corr, kc, problem, A, init, Qtab, Stab, LOtab, out);
}

// Round 7
// 226.715 us; speedup vs baseline: 2.0280x; 1.1073x over previous
//
#include <hip/hip_runtime.h>
#include <math.h>

#define B_  1024
#define T_  500
#define K_  100
#define NP_ 10000
#define CH  32          // steps per chunk
#define NCH 16          // 16*32 = 512 >= T_

__device__ __forceinline__ float lse2(float a, float b) {
    float m = fmaxf(a, b);
    return m + __logf(__expf(a - m) + __expf(b - m));
}

template<int CTRL, int RM>
__device__ __forceinline__ float dpp_add(float v) {
    int x = __builtin_amdgcn_update_dpp(0, __float_as_int(v), CTRL, RM, 0xf, true);
    return v + __int_as_float(x);
}

// Full-wave64 sum via DPP (pure VALU, no LDS). Result uniform via readlane(63).
__device__ __forceinline__ float wave_sum(float v) {
    v = dpp_add<0x111, 0xf>(v);   // row_shr:1
    v = dpp_add<0x112, 0xf>(v);   // row_shr:2
    v = dpp_add<0x114, 0xf>(v);   // row_shr:4
    v = dpp_add<0x118, 0xf>(v);   // row_shr:8
    v = dpp_add<0x142, 0xa>(v);   // row_bcast:15 -> rows 1,3
    v = dpp_add<0x143, 0xc>(v);   // row_bcast:31 -> rows 2,3
    return __int_as_float(__builtin_amdgcn_readlane(__float_as_int(v), 63));
}

// async global->LDS DMA: per-lane global src, linear LDS dest (base + lane*size)
#define GLOAD16(gp, lp) __builtin_amdgcn_global_load_lds( \
    (const __attribute__((address_space(1))) unsigned int*)(gp), \
    (__attribute__((address_space(3))) unsigned int*)(lp), 16, 0, 0)
#define GLOAD4(gp, lp) __builtin_amdgcn_global_load_lds( \
    (const __attribute__((address_space(1))) unsigned int*)(gp), \
    (__attribute__((address_space(3))) unsigned int*)(lp), 4, 0, 0)
#define WAITV0 asm volatile("s_waitcnt vmcnt(0)" ::: "memory")

// ---------------- precompute (unchanged, validated) ----------
__global__ __launch_bounds__(64, 4) void bkt_pre(
    const float* __restrict__ A, const float* __restrict__ trans,
    const float* __restrict__ obs, float* __restrict__ Qtab,
    float* __restrict__ Stab, float* __restrict__ LOtab)
{
    const int p = blockIdx.x;
    const int lane = threadIdx.x;
    const int k0 = lane, k1 = lane + 64;
    const bool has1 = (k1 < K_);
    const int k1c = has1 ? k1 : k0;
    const float m1 = has1 ? 1.f : 0.f;

    float4 t0 = *reinterpret_cast<const float4*>(trans + k0 * 4);
    float l00 = lse2(t0.x, t0.z), l01 = lse2(t0.y, t0.w);
    float lt000 = t0.x - l00, lt001 = t0.y - l01;
    float lt010 = t0.z - l00, lt011 = t0.w - l01;
    float4 t1 = *reinterpret_cast<const float4*>(trans + k1c * 4);
    float l10 = lse2(t1.x, t1.z), l11 = lse2(t1.y, t1.w);
    float lt100 = t1.x - l10, lt101 = t1.y - l11;
    float lt110 = t1.z - l10, lt111 = t1.w - l11;

    const float* ar = A + (size_t)p * K_;
    float c0 = ar[k0];
    float c1 = ar[k1c] * m1;

    float sc  = wave_sum(c0 + c1);
    float q00 = wave_sum(c0 * lt000 + c1 * lt100);
    float q01 = wave_sum(c0 * lt001 + c1 * lt101);
    float q10 = wave_sum(c0 * lt010 + c1 * lt110);
    float q11 = wave_sum(c0 * lt011 + c1 * lt111);

    float4 ob = *reinterpret_cast<const float4*>(obs + (size_t)p * 4);
    float l0 = lse2(ob.x, ob.y), l1 = lse2(ob.z, ob.w);

    if (lane == 0) {
        reinterpret_cast<float4*>(Qtab)[p] = make_float4(q00, q01, q10, q11);
        Stab[p] = sc;
        reinterpret_cast<float4*>(LOtab)[p] =
            make_float4(ob.x - l0, ob.y - l0, ob.z - l1, ob.w - l1);
    }
}

// ---------------- main scan: prefetched-register pipeline ----------------
__global__ __launch_bounds__(64, 1) void bkt_main(
    const int* __restrict__ corr, const int* __restrict__ kc,
    const int* __restrict__ problem, const float* __restrict__ A,
    const float* __restrict__ init, const float* __restrict__ Qtab,
    const float* __restrict__ Stab, const float* __restrict__ LOtab,
    float* __restrict__ out)
{
    const int b = blockIdx.x;
    const int lane = threadIdx.x;
    const int k1 = lane + 64;
    const bool has1 = (k1 < K_);
    const int k1c = has1 ? k1 : lane;
    const float m1 = has1 ? 1.f : 0.f;

    // LDS staging buffers (~29.2 KB)
    __shared__ float  s_c[2][CH * K_];       // A-rows per step      25600 B
    __shared__ float4 s_ql[2][2 * CH];       // Q[0..31] L[32..63]    2048 B
    __shared__ float  s_s[2][CH];            //                        256 B
    __shared__ int    s_kcpr[3][2 * CH];     // kc[0..31] pr[32..63]   768 B
    __shared__ int    s_y[3][CH];            //                        384 B

    const int* kcb = kc + (size_t)b * T_;
    const int* prb = problem + (size_t)b * T_;
    const int* cob = corr + (size_t)b * T_;
    float* outp = out + (size_t)b * T_ * 2;

    // alpha init: log_softmax(init_logits, axis=1)
    float al00, al01, al10 = 0.f, al11 = 0.f;
    {
        float2 x = *reinterpret_cast<const float2*>(init + lane * 2);
        float l = lse2(x.x, x.y);
        al00 = x.x - l; al01 = x.y - l;
    }
    {
        float2 x = *reinterpret_cast<const float2*>(init + k1c * 2);
        float l = lse2(x.x, x.y);
        al10 = (x.x - l) * m1; al11 = (x.y - l) * m1;
    }

#define STAGEIDX(cn, ib) {                                                \
        int tt_ = (cn) * CH + (lane & 31);                                \
        tt_ = tt_ < T_ ? tt_ : T_ - 1;                                    \
        const int* is_ = (lane < 32 ? kcb : prb) + tt_;                   \
        GLOAD4(is_, &s_kcpr[ib][0]);                                      \
        if (lane < 32) GLOAD4(cob + tt_, &s_y[ib][0]);                    \
    }

#define GATHER(ib, db) {                                                  \
        int myidx_ = s_kcpr[ib][lane];                                    \
        const float* qlsrc_ = (lane < 32)                                 \
            ? (Qtab  + (size_t)myidx_ * 4)                                \
            : (LOtab + (size_t)myidx_ * 4);                               \
        GLOAD16(qlsrc_, &s_ql[db][0]);                                    \
        if (lane < 32) GLOAD4(Stab + myidx_, &s_s[db][0]);                \
        _Pragma("unroll")                                                 \
        for (int j_ = 0; j_ < 13; ++j_) {                                 \
            int f_ = j_ * 64 + lane;                                      \
            unsigned tf_ = ((unsigned)f_ * 5243u) >> 17;    /* f/25 */    \
            int q_ = f_ - (int)tf_ * 25;                                  \
            int kcv_ = s_kcpr[ib][tf_];                                   \
            const float* asrc_ = A + (size_t)kcv_ * K_ + q_ * 4;          \
            if (f_ < CH * 25) GLOAD16(asrc_, &s_c[db][j_ * 256]);         \
        }                                                                 \
    }

    // ---- prologue: stage idx for chunks 0,1; gather chunk 0 ----
    STAGEIDX(0, 0);
    STAGEIDX(1, 1);
    WAITV0;
    GATHER(0, 0);

#pragma unroll 1
    for (int n = 0; n < NCH; ++n) {
        WAITV0;                               // chunk-n data + idx n+1 landed
        { int i2 = (n + 2) % 3; STAGEIDX(n + 2, i2); }
        { int i1 = (n + 1) % 3, d1 = (n + 1) & 1; GATHER(i1, d1); }

        const float*  cbuf = s_c[n & 1];
        const float4* qlb  = s_ql[n & 1];
        const float*  sb   = s_s[n & 1];
        const int*    yb   = s_y[n % 3];
        const int base = n * CH;

        // ---- prime a2 for step base+0 from fresh alpha ----
        float ca0 = cbuf[lane];
        float ca1 = cbuf[k1c] * m1;
        float a20 = wave_sum(ca0 * al00 + ca1 * al10);
        float a21 = wave_sum(ca0 * al01 + ca1 * al11);

        // lane u keeps (a20,a21) of step u for the epilogue
        float keep0 = 0.f, keep1 = 0.f;

        // ---- prefetch step-0 operands + c of step 1 ----
        float4 Q = qlb[0];
        float4 L = qlb[CH];
        float  S = sb[0];
        int    y = yb[0];
        float cb0 = cbuf[K_ + lane];
        float cb1 = cbuf[K_ + k1c] * m1;

        // ---- steps 0..CH-2: short-chain recurrence, fully unrolled ----
#pragma unroll
        for (int u = 0; u < CH - 1; ++u) {
            keep0 = (lane == u) ? a20 : keep0;
            keep1 = (lane == u) ? a21 : keep1;
            float hs0 = ((y == 0) ? L.x : L.y) * S;
            float hs1 = ((y == 0) ? L.z : L.w) * S;
            // W/U prep (independent of a3)
            float x0 = cb0 * ca0, x1 = cb1 * ca1;
            float tu0 = cb0 - x0, tu1 = cb1 - x1;
            float U0 = wave_sum(tu0 * al00 + tu1 * al10);
            float U1 = wave_sum(tu0 * al01 + tu1 * al11);
            float Wv = wave_sum(x0 + x1);
            // critical scalar chain
            float a30 = lse2(hs0 + Q.x + a20, hs1 + Q.y + a21);
            float a31 = lse2(hs0 + Q.z + a20, hs1 + Q.w + a21);
            // alpha update (uses pre-update alpha in U above: source order)
            al00 += ca0 * (a30 - al00);
            al01 += ca0 * (a31 - al01);
            al10 += ca1 * (a30 - al10);
            al11 += ca1 * (a31 - al11);
            // next a2 = U + W*a3
            a20 = U0 + Wv * a30;
            a21 = U1 + Wv * a31;
            ca0 = cb0; ca1 = cb1;
            // prefetch step u+1 operands (compile-time offsets; issue early)
            Q = qlb[u + 1];
            L = qlb[CH + u + 1];
            S = sb[u + 1];
            y = yb[u + 1];
            if (u + 2 < CH) {
                cb0 = cbuf[(u + 2) * K_ + lane];
                cb1 = cbuf[(u + 2) * K_ + k1c] * m1;
            }
        }
        // ---- last step of chunk (no next-a2 needed) ----
        {
            keep0 = (lane == (CH - 1)) ? a20 : keep0;
            keep1 = (lane == (CH - 1)) ? a21 : keep1;
            float hs0 = ((y == 0) ? L.x : L.y) * S;
            float hs1 = ((y == 0) ? L.z : L.w) * S;
            float a30 = lse2(hs0 + Q.x + a20, hs1 + Q.y + a21);
            float a31 = lse2(hs0 + Q.z + a20, hs1 + Q.w + a21);
            al00 += ca0 * (a30 - al00);
            al01 += ca0 * (a31 - al01);
            al10 += ca1 * (a30 - al10);
            al11 += ca1 * (a31 - al11);
        }
        // ---- epilogue: batched py for the chunk (lanes 0..31, one step each) ----
        if (lane < 32) {
            float4 Le = qlb[CH + lane];
            float  Se = sb[lane];
            float h00 = Le.x * Se, h01 = Le.y * Se, h10 = Le.z * Se, h11 = Le.w * Se;
            float py0 = lse2(h00 + keep0, h10 + keep1);
            float py1 = lse2(h01 + keep0, h11 + keep1);
            float nrm = lse2(py0, py1);
            int t = base + lane;
            if (t < T_)
                *reinterpret_cast<float2*>(outp + (size_t)t * 2) =
                    make_float2(py0 - nrm, py1 - nrm);
        }
    }
#undef STAGEIDX
#undef GATHER
}

extern "C" void kernel_launch(void* const* d_in, const int* in_sizes, int n_in,
                              void* d_out, int out_size, void* d_ws, size_t ws_size,
                              hipStream_t stream) {
    const int*   corr    = (const int*)d_in[0];
    const int*   kc      = (const int*)d_in[1];
    const int*   problem = (const int*)d_in[2];
    const float* A       = (const float*)d_in[3];
    const float* trans   = (const float*)d_in[4];
    const float* obs     = (const float*)d_in[5];
    const float* init    = (const float*)d_in[6];
    float* out = (float*)d_out;

    // workspace layout: Qtab (NP*4 f32) | LOtab (NP*4 f32) | Stab (NP f32)
    float* Qtab  = (float*)d_ws;
    float* LOtab = Qtab + (size_t)NP_ * 4;
    float* Stab  = LOtab + (size_t)NP_ * 4;

    bkt_pre<<<NP_, 64, 0, stream>>>(A, trans, obs, Qtab, Stab, LOtab);
    bkt_main<<<B_, 64, 0, stream>>>(corr, kc, problem, A, init, Qtab, Stab, LOtab, out);
}